// Round 1
// 1375.032 us; speedup vs baseline: 1.0635x; 1.0635x over previous
//
#include <hip/hip_runtime.h>
#include <math.h>

#define N_ATOMS 20000
#define N_CG    1000
#define N_EDGES 200000
#define FEAT    128
#define NRBF    20
#define NCONV   3
#define CUTOFF  5.0f
#define PLANE   (N_ATOMS * FEAT)      // 2,560,000
#define PI_F    3.14159265358979323846f
#define LDH     130                   // LDS H stride (f32) — bank-conflict-safe

#define PACK_PER_CONV 212992          // ushorts per conv in each of packH/packL

typedef __attribute__((ext_vector_type(8))) short bf16x8;
typedef __attribute__((ext_vector_type(4))) float f32x4;

__device__ __forceinline__ void split2(float x, ushort& h, ushort& l)
{
    unsigned u  = __float_as_uint(x);
    unsigned hb = (u + 0x7FFFu + ((u >> 16) & 1u)) & 0xFFFF0000u;
    float    hf = __uint_as_float(hb);
    float    lf = x - hf;                       // exact
    unsigned ul = __float_as_uint(lf);
    h = (ushort)(hb >> 16);
    l = (ushort)((ul + 0x7FFFu + ((ul >> 16) & 1u)) >> 16);
}

__device__ __forceinline__ void splitv8(const float* hv, bf16x8& ah, bf16x8& al)
{
#pragma unroll
    for (int j = 0; j < 8; ++j) {
        ushort h, l;
        split2(hv[j], h, l);
        ah[j] = (short)h; al[j] = (short)l;
    }
}

// 3-MFMA split product accumulate
#define MFMA3(ACC, AH_, AL_, BH_, BL_)                                              \
    ACC = __builtin_amdgcn_mfma_f32_16x16x32_bf16(AH_, BH_, ACC, 0, 0, 0);          \
    ACC = __builtin_amdgcn_mfma_f32_16x16x32_bf16(AH_, BL_, ACC, 0, 0, 0);          \
    ACC = __builtin_amdgcn_mfma_f32_16x16x32_bf16(AL_, BH_, ACC, 0, 0, 0);

// ---------------------------------------------------------------------------
// Fused MLP: C = (swish(A @ B1 + b1)) @ B2 + b2[bcol0:].  A packed bf16 hi/lo
// [M][K1]; B1 [128][K1] packed; B2 [N2][128] packed; H held in LDS fp32.
// Block = 32 rows, 256 thr (4 waves 2x2). M must be divisible by 32.
// ---------------------------------------------------------------------------
template<int K1, int N2>
__global__ __launch_bounds__(256)
void mlp_fused(const ushort* __restrict__ AH, const ushort* __restrict__ AL,
               const ushort* __restrict__ B1h, const ushort* __restrict__ B1l,
               const float* __restrict__ b1,
               const ushort* __restrict__ B2h, const ushort* __restrict__ B2l,
               const float* __restrict__ b2, int bcol0,
               float* __restrict__ C)
{
    __shared__ float Hs[32 * LDH];
    const int tid  = threadIdx.x;
    const int lane = tid & 63;
    const int w    = tid >> 6;
    const int wm   = w & 1, wn = w >> 1;
    const int m0   = blockIdx.x * 32;
    const int l15  = lane & 15;
    const int koff = (lane >> 4) * 8;
    const int rowb = wm * 16;                   // local row base
    const int q4   = (lane >> 4) * 4;

    // ---- phase 1: H = swish(A @ B1 + b1) (N1 = 128) ----
    f32x4 acc1[4];
#pragma unroll
    for (int j = 0; j < 4; ++j) acc1[j] = (f32x4){0.f, 0.f, 0.f, 0.f};
    for (int k0 = 0; k0 < K1; k0 += 32) {
        size_t aa = (size_t)(m0 + rowb + l15) * K1 + k0 + koff;
        bf16x8 ah = *reinterpret_cast<const bf16x8*>(AH + aa);
        bf16x8 al = *reinterpret_cast<const bf16x8*>(AL + aa);
#pragma unroll
        for (int nf = 0; nf < 4; ++nf) {
            size_t ba = (size_t)(wn * 64 + nf * 16 + l15) * K1 + k0 + koff;
            bf16x8 bh = *reinterpret_cast<const bf16x8*>(B1h + ba);
            bf16x8 bl = *reinterpret_cast<const bf16x8*>(B1l + ba);
            MFMA3(acc1[nf], ah, al, bh, bl);
        }
    }
#pragma unroll
    for (int nf = 0; nf < 4; ++nf) {
        int col = wn * 64 + nf * 16 + l15;
        float bv = b1[col];
#pragma unroll
        for (int r = 0; r < 4; ++r) {
            float x = acc1[nf][r] + bv;
            x = x / (1.f + __expf(-x));         // swish
            Hs[(rowb + q4 + r) * LDH + col] = x;
        }
    }
    __syncthreads();

    // ---- phase 2: C = H @ B2 + b2 ----
    constexpr int NF2  = N2 / 32;               // frags per wave
    constexpr int WCOL = N2 / 2;
    f32x4 acc2[NF2];
#pragma unroll
    for (int j = 0; j < NF2; ++j) acc2[j] = (f32x4){0.f, 0.f, 0.f, 0.f};
    for (int k0 = 0; k0 < 128; k0 += 32) {
        const float* hp = &Hs[(rowb + l15) * LDH + k0 + koff];
        float hv[8];
#pragma unroll
        for (int j = 0; j < 4; ++j) hv[j] = hp[j];
#pragma unroll
        for (int j = 0; j < 4; ++j) hv[4 + j] = hp[4 + j];
        bf16x8 ah, al;
        splitv8(hv, ah, al);
#pragma unroll
        for (int nf = 0; nf < NF2; ++nf) {
            size_t ba = (size_t)(wn * WCOL + nf * 16 + l15) * 128 + k0 + koff;
            bf16x8 bh = *reinterpret_cast<const bf16x8*>(B2h + ba);
            bf16x8 bl = *reinterpret_cast<const bf16x8*>(B2l + ba);
            MFMA3(acc2[nf], ah, al, bh, bl);
        }
    }
#pragma unroll
    for (int nf = 0; nf < NF2; ++nf) {
        int col = wn * WCOL + nf * 16 + l15;
        float bv = b2 ? b2[bcol0 + col] : 0.f;
#pragma unroll
        for (int r = 0; r < 4; ++r) {
            int row = m0 + rowb + q4 + r;
            C[(size_t)row * N2 + col] = acc2[nf][r] + bv;
        }
    }
}

// ---------------------------------------------------------------------------
// upd_V over 3 planes + fused norm + Ccat norm-half pack.
// A = packed v (3 planes), B = upd_V. Writes vv fp32 (3 planes) + Ccat[,128:].
// ---------------------------------------------------------------------------
__global__ __launch_bounds__(256)
void gemm_vnorm(const ushort* __restrict__ vHp, const ushort* __restrict__ vLp,
                const ushort* __restrict__ Bh, const ushort* __restrict__ Bl,
                float* __restrict__ vv,
                ushort* __restrict__ CcatH, ushort* __restrict__ CcatL)
{
    const int tid  = threadIdx.x;
    const int lane = tid & 63;
    const int w    = tid >> 6;
    const int wm   = w & 1, wn = w >> 1;
    const int m0   = blockIdx.x * 32;
    const int l15  = lane & 15;
    const int koff = (lane >> 4) * 8;
    const int rowb = wm * 16;
    const int q4   = (lane >> 4) * 4;

    f32x4 acc[3][4];
#pragma unroll
    for (int d = 0; d < 3; ++d)
#pragma unroll
        for (int j = 0; j < 4; ++j) acc[d][j] = (f32x4){0.f, 0.f, 0.f, 0.f};

    for (int k0 = 0; k0 < 128; k0 += 32) {
        bf16x8 ah[3], al[3];
#pragma unroll
        for (int d = 0; d < 3; ++d) {
            size_t aa = (size_t)d * PLANE + (size_t)(m0 + rowb + l15) * 128 + k0 + koff;
            ah[d] = *reinterpret_cast<const bf16x8*>(vHp + aa);
            al[d] = *reinterpret_cast<const bf16x8*>(vLp + aa);
        }
#pragma unroll
        for (int nf = 0; nf < 4; ++nf) {
            size_t ba = (size_t)(wn * 64 + nf * 16 + l15) * 128 + k0 + koff;
            bf16x8 bh = *reinterpret_cast<const bf16x8*>(Bh + ba);
            bf16x8 bl = *reinterpret_cast<const bf16x8*>(Bl + ba);
#pragma unroll
            for (int d = 0; d < 3; ++d) {
                MFMA3(acc[d][nf], ah[d], al[d], bh, bl);
            }
        }
    }
#pragma unroll
    for (int nf = 0; nf < 4; ++nf) {
        int col = wn * 64 + nf * 16 + l15;
#pragma unroll
        for (int r = 0; r < 4; ++r) {
            int row = m0 + rowb + q4 + r;
            int idx = row * FEAT + col;
            float x = acc[0][nf][r], y = acc[1][nf][r], z = acc[2][nf][r];
            vv[idx] = x; vv[PLANE + idx] = y; vv[2 * PLANE + idx] = z;
            float nrm = sqrtf(x * x + y * y + z * z + 3e-15f);
            ushort h, l;
            split2(nrm, h, l);
            CcatH[(size_t)row * 256 + 128 + col] = h;
            CcatL[(size_t)row * 256 + 128 + col] = l;
        }
    }
}

// ---------------------------------------------------------------------------
// upd_U over 3 planes + fused update rule.
// u_v in-register; reads vv/stack/v/s; writes s, v (fp32 + packed).
// Blocks own disjoint rows -> in-place overwrite of packed v is race-free.
// ---------------------------------------------------------------------------
__global__ __launch_bounds__(256)
void gemm_u_update(const ushort* __restrict__ vHp, const ushort* __restrict__ vLp,
                   const ushort* __restrict__ Bh, const ushort* __restrict__ Bl,
                   const float* __restrict__ vv, const float* __restrict__ stack,
                   float* __restrict__ s, float* __restrict__ v,
                   ushort* __restrict__ sH, ushort* __restrict__ sL)
{
    const int tid  = threadIdx.x;
    const int lane = tid & 63;
    const int w    = tid >> 6;
    const int wm   = w & 1, wn = w >> 1;
    const int m0   = blockIdx.x * 32;
    const int l15  = lane & 15;
    const int koff = (lane >> 4) * 8;
    const int rowb = wm * 16;
    const int q4   = (lane >> 4) * 4;

    f32x4 acc[3][4];
#pragma unroll
    for (int d = 0; d < 3; ++d)
#pragma unroll
        for (int j = 0; j < 4; ++j) acc[d][j] = (f32x4){0.f, 0.f, 0.f, 0.f};

    for (int k0 = 0; k0 < 128; k0 += 32) {
        bf16x8 ah[3], al[3];
#pragma unroll
        for (int d = 0; d < 3; ++d) {
            size_t aa = (size_t)d * PLANE + (size_t)(m0 + rowb + l15) * 128 + k0 + koff;
            ah[d] = *reinterpret_cast<const bf16x8*>(vHp + aa);
            al[d] = *reinterpret_cast<const bf16x8*>(vLp + aa);
        }
#pragma unroll
        for (int nf = 0; nf < 4; ++nf) {
            size_t ba = (size_t)(wn * 64 + nf * 16 + l15) * 128 + k0 + koff;
            bf16x8 bh = *reinterpret_cast<const bf16x8*>(Bh + ba);
            bf16x8 bl = *reinterpret_cast<const bf16x8*>(Bl + ba);
#pragma unroll
            for (int d = 0; d < 3; ++d) {
                MFMA3(acc[d][nf], ah[d], al[d], bh, bl);
            }
        }
    }
    // packed v overwrite below is safe: this block's A reads (own rows) are done
    ushort* vHo = const_cast<ushort*>(vHp);
    ushort* vLo = const_cast<ushort*>(vLp);
#pragma unroll
    for (int nf = 0; nf < 4; ++nf) {
        int col = wn * 64 + nf * 16 + l15;
#pragma unroll
        for (int r = 0; r < 4; ++r) {
            int row = m0 + rowb + q4 + r;
            int idx = row * FEAT + col;
            const float* st = stack + (size_t)row * 384 + col;
            float avv = st[0], asv = st[128], ass = st[256];
            float u0 = acc[0][nf][r], u1 = acc[1][nf][r], u2 = acc[2][nf][r];
            float w0 = vv[idx], w1 = vv[PLANE + idx], w2 = vv[2 * PLANE + idx];
            float dot = u0 * w0 + u1 * w1 + u2 * w2;
            float n0 = v[idx]             + u0 * avv;
            float n1 = v[PLANE + idx]     + u1 * avv;
            float n2 = v[2 * PLANE + idx] + u2 * avv;
            v[idx] = n0; v[PLANE + idx] = n1; v[2 * PLANE + idx] = n2;
            ushort h, l;
            split2(n0, h, l); vHo[idx] = h;             vLo[idx] = l;
            split2(n1, h, l); vHo[PLANE + idx] = h;     vLo[PLANE + idx] = l;
            split2(n2, h, l); vHo[2 * PLANE + idx] = h; vLo[2 * PLANE + idx] = l;
            float ns = s[idx] + dot * asv + ass;
            s[idx] = ns;
            split2(ns, h, l); sH[idx] = h; sL[idx] = l;
        }
    }
}

// ---------------------------------------------------------------------------
// Weight pre-pack: fp32 W[k][col0+n] -> bf16 hi/lo at [n][k] (k-contiguous).
// ---------------------------------------------------------------------------
__global__ void k_pack_all(const float* __restrict__ msg_W1, const float* __restrict__ msg_W2,
                           const float* __restrict__ upd_V,  const float* __restrict__ upd_W1,
                           const float* __restrict__ upd_W2, const float* __restrict__ upd_U,
                           const float* __restrict__ cg_W1,  const float* __restrict__ cg_W2,
                           ushort* __restrict__ Bh, ushort* __restrict__ Bl)
{
    const int wid = blockIdx.y, conv = blockIdx.z;
    const float* W; int K, N, ldw, col0; size_t off;
    switch (wid) {
        case 0: W = msg_W1 + (size_t)conv * 16384; K = 128; N = 128; ldw = 128; col0 = 0;   off = 0;      break;
        case 1: W = msg_W2 + (size_t)conv * 49152; K = 128; N = 384; ldw = 384; col0 = 0;   off = 16384;  break;
        case 2: W = upd_V  + (size_t)conv * 16384; K = 128; N = 128; ldw = 128; col0 = 0;   off = 65536;  break;
        case 3: W = upd_W1 + (size_t)conv * 32768; K = 256; N = 128; ldw = 128; col0 = 0;   off = 81920;  break;
        case 4: W = upd_W2 + (size_t)conv * 49152; K = 128; N = 384; ldw = 384; col0 = 0;   off = 114688; break;
        case 5: W = upd_U  + (size_t)conv * 16384; K = 128; N = 128; ldw = 128; col0 = 0;   off = 163840; break;
        case 6: W = cg_W1  + (size_t)conv * 16384; K = 128; N = 128; ldw = 128; col0 = 0;   off = 180224; break;
        default:W = cg_W2  + (size_t)conv * 49152; K = 128; N = 128; ldw = 384; col0 = 128; off = 196608; break;
    }
    off += (size_t)conv * PACK_PER_CONV;
    int idx = blockIdx.x * 256 + threadIdx.x;
    if (idx >= K * N) return;
    int k = idx & (K - 1);
    int n = idx >> ((K == 256) ? 8 : 7);
    ushort h, l;
    split2(W[(size_t)k * ldw + col0 + n], h, l);
    Bh[off + (size_t)n * K + k] = h;
    Bl[off + (size_t)n * K + k] = l;
}

// ---------------------------------------------------------------------------
// Setup kernels
// ---------------------------------------------------------------------------
__global__ void k_s_init(const int* __restrict__ z, const float* __restrict__ embed,
                         float* __restrict__ s, ushort* __restrict__ sH, ushort* __restrict__ sL)
{
    int idx = blockIdx.x * blockDim.x + threadIdx.x;
    if (idx >= PLANE) return;
    int n = idx >> 7, g = idx & 127;
    float e = embed[z[n] * FEAT + g];
    s[idx] = e;
    ushort h, l;
    split2(e, h, l);
    sH[idx] = h; sL[idx] = l;
}

__global__ void k_atom_geo(const int* __restrict__ mapping,
                           const float* __restrict__ xyz, const float* __restrict__ cg_xyz,
                           float* __restrict__ rbf_a, float* __restrict__ env_a,
                           float* __restrict__ cnt)
{
    int n = blockIdx.x * blockDim.x + threadIdx.x;
    if (n >= N_ATOMS) return;
    int m = mapping[n];
    float dx = xyz[n * 3 + 0] - cg_xyz[m * 3 + 0];
    float dy = xyz[n * 3 + 1] - cg_xyz[m * 3 + 1];
    float dz = xyz[n * 3 + 2] - cg_xyz[m * 3 + 2];
    float d = sqrtf(dx * dx + dy * dy + dz * dz + 3e-15f);
    float env = (d < CUTOFF) ? 0.5f * (cosf(PI_F * d / CUTOFF) + 1.f) : 0.f;
    env_a[n] = env;
    float s = env / d;
#pragma unroll
    for (int k = 0; k < NRBF; ++k)
        rbf_a[n * NRBF + k] = sinf((k + 1) * PI_F * d / CUTOFF) * s;
    atomicAdd(&cnt[m], 1.f);
}

// ---------------------------------------------------------------------------
// CSR build
// ---------------------------------------------------------------------------
__global__ void k_deg(const int* __restrict__ nbr, int* __restrict__ deg)
{
    int e = blockIdx.x * blockDim.x + threadIdx.x;
    if (e < N_EDGES) atomicAdd(&deg[nbr[2 * e]], 1);
}

__global__ __launch_bounds__(1024)
void k_scan(const int* __restrict__ deg, int* __restrict__ rowptr)
{
    __shared__ int sh[1024];
    const int chunk = (N_ATOMS + 1023) / 1024;
    int t = threadIdx.x;
    int base = t * chunk;
    int sum = 0;
    for (int i = 0; i < chunk; ++i) {
        int idx = base + i;
        if (idx < N_ATOMS) sum += deg[idx];
    }
    sh[t] = sum;
    __syncthreads();
    for (int off = 1; off < 1024; off <<= 1) {
        int val = (t >= off) ? sh[t - off] : 0;
        __syncthreads();
        sh[t] += val;
        __syncthreads();
    }
    int run = (t == 0) ? 0 : sh[t - 1];
    for (int i = 0; i < chunk; ++i) {
        int idx = base + i;
        if (idx < N_ATOMS) { rowptr[idx] = run; run += deg[idx]; }
    }
}

__global__ void k_fill(const int* __restrict__ nbr, const float* __restrict__ xyz,
                       const int* __restrict__ rowptr, int* __restrict__ cursor,
                       int* __restrict__ rec_dst, float4* __restrict__ rec_u4,
                       float* __restrict__ rec_rbf)
{
    int e = blockIdx.x * blockDim.x + threadIdx.x;
    if (e >= N_EDGES) return;
    int src = nbr[2 * e], dst = nbr[2 * e + 1];
    int pos = atomicAdd(&cursor[src], 1);
    int q = rowptr[src] + pos;
    float dx = xyz[dst * 3 + 0] - xyz[src * 3 + 0];
    float dy = xyz[dst * 3 + 1] - xyz[src * 3 + 1];
    float dz = xyz[dst * 3 + 2] - xyz[src * 3 + 2];
    float d = sqrtf(dx * dx + dy * dy + dz * dz + 3e-15f);
    float env = (d < CUTOFF) ? 0.5f * (cosf(PI_F * d / CUTOFF) + 1.f) : 0.f;
    rec_dst[q] = dst;
    rec_u4[q] = make_float4(dx / d, dy / d, dz / d, env);
    float sc = env / d;
#pragma unroll
    for (int k = 0; k < NRBF; ++k)
        rec_rbf[(size_t)q * NRBF + k] = sinf((k + 1) * PI_F * d / CUTOFF) * sc;
}

// ---------------------------------------------------------------------------
// Edge segment-sum.  r0 change: the 21x3 dist-weight table is held in VGPRs
// (63 regs/lane, lane <-> feature) instead of a 43 KB LDS tile, eliminating
// 21 ds_read_b128 per edge per lane (~180 us/conv of LDS traffic).  Blocks
// grid-stride over atoms so the weight-load prologue amortizes ~8x.
// Accumulation order (4 slots, stride-4 over edges) is unchanged.
// ---------------------------------------------------------------------------
#define EDGE_BLOCKS 2500
__global__ __launch_bounds__(512, 4)
void k_edge_seg(const int* __restrict__ rowptr, const int* __restrict__ deg,
                const int* __restrict__ rec_dst, const float4* __restrict__ rec_u4,
                const float* __restrict__ rec_rbf,
                const float* __restrict__ phi,
                const float* __restrict__ v_in, float* __restrict__ v_out,
                float* __restrict__ s,
                ushort* __restrict__ vH, ushort* __restrict__ vL,
                ushort* __restrict__ CcatH, ushort* __restrict__ CcatL,
                const float* __restrict__ distW, const float* __restrict__ distb)
{
    __shared__ f32x4 red[512];                  // 8 KB reduce buffer
    const int tid  = threadIdx.x;
    const int slot = tid >> 7;
    const int f    = tid & 127;

    // per-lane weight registers: wk[k].{x,y,z}, k=20 is the bias row
    float wx[21], wy[21], wz[21];
#pragma unroll
    for (int k = 0; k < NRBF; ++k) {
        wx[k] = distW[k * 384 + f];
        wy[k] = distW[k * 384 + 128 + f];
        wz[k] = distW[k * 384 + 256 + f];
    }
    wx[20] = distb[f];
    wy[20] = distb[128 + f];
    wz[20] = distb[256 + f];

    for (int a = blockIdx.x; a < N_ATOMS; a += EDGE_BLOCKS) {
        const int beg = rowptr[a];
        const int end = beg + deg[a];
        float s_acc = 0.f, vx = 0.f, vy = 0.f, vz = 0.f;

        for (int p = beg + slot; p < end; p += 4) {
            float4 u4 = rec_u4[p];
            int dst = rec_dst[p];
            if (u4.w == 0.f) continue;          // fully-dead edge
            const float* ph = phi + (size_t)dst * 384 + f;
            float p0 = ph[0], p1 = ph[128], p2 = ph[256];
            int di = dst * FEAT + f;
            float vdx = v_in[di], vdy = v_in[PLANE + di], vdz = v_in[2 * PLANE + di];
            const float4* rbp = reinterpret_cast<const float4*>(rec_rbf + (size_t)p * NRBF);
            float4 r0 = rbp[0], r1 = rbp[1], r2 = rbp[2], r3 = rbp[3], r4 = rbp[4];
            const float rr[21] = {r0.x, r0.y, r0.z, r0.w, r1.x, r1.y, r1.z, r1.w,
                                  r2.x, r2.y, r2.z, r2.w, r3.x, r3.y, r3.z, r3.w,
                                  r4.x, r4.y, r4.z, r4.w, u4.w};
            float w0 = 0.f, w1 = 0.f, w2 = 0.f;
#pragma unroll
            for (int k = 0; k < 21; ++k) {
                w0 += rr[k] * wx[k];
                w1 += rr[k] * wy[k];
                w2 += rr[k] * wz[k];
            }
            float i0 = p0 * w0, i1 = p1 * w1, i2 = p2 * w2;
            vx += i2 * u4.x + i0 * vdx;
            vy += i2 * u4.y + i0 * vdy;
            vz += i2 * u4.z + i0 * vdz;
            s_acc += i1;
        }

        __syncthreads();                        // prior atom's reduce reads done
        red[tid] = (f32x4){s_acc, vx, vy, vz};
        __syncthreads();
        if (slot == 0) {
            f32x4 t = red[f] + red[128 + f] + red[256 + f] + red[384 + f];
            int si = a * FEAT + f;
            float ns = s[si] + t.x;
            s[si] = ns;
            float nx = v_in[si]             + t.y;
            float ny = v_in[PLANE + si]     + t.z;
            float nz = v_in[2 * PLANE + si] + t.w;
            v_out[si] = nx; v_out[PLANE + si] = ny; v_out[2 * PLANE + si] = nz;
            ushort h, l;
            split2(nx, h, l); vH[si] = h;             vL[si] = l;
            split2(ny, h, l); vH[PLANE + si] = h;     vL[PLANE + si] = l;
            split2(nz, h, l); vH[2 * PLANE + si] = h; vL[2 * PLANE + si] = l;
            split2(ns, h, l);
            CcatH[(size_t)a * 256 + f] = h;
            CcatL[(size_t)a * 256 + f] = l;
        }
    }
}

// CG message; conv0 also scatters s (s_add path)
__global__ __launch_bounds__(128)
void k_cg_msg(const int* __restrict__ mapping, const float* __restrict__ phi_mid,
              const float* __restrict__ rbf_a, const float* __restrict__ env_a,
              const float* __restrict__ distW, const float* __restrict__ distb,
              const float* __restrict__ s_add, float* __restrict__ S_acc)
{
    int n = blockIdx.x;
    float env = env_a[n];
    int f = threadIdx.x;
    if (env == 0.f && s_add == nullptr) return;
    float val = s_add ? s_add[n * FEAT + f] : 0.f;
    if (env != 0.f) {
        __shared__ float sh_rbf[NRBF];
        if (f < NRBF) sh_rbf[f] = rbf_a[n * NRBF + f];
        __syncthreads();
        float w1 = 0.f;
#pragma unroll
        for (int k = 0; k < NRBF; ++k)
            w1 += sh_rbf[k] * distW[k * 384 + 128 + f];
        w1 += distb[128 + f] * env;
        val += phi_mid[n * FEAT + f] * w1;
    }
    atomicAdd(&S_acc[mapping[n] * FEAT + f], val);
}

__global__ void k_finalize(const float* __restrict__ S_acc, const float* __restrict__ cnt,
                           float* __restrict__ out, int add)
{
    int idx = blockIdx.x * blockDim.x + threadIdx.x;
    if (idx >= N_CG * FEAT) return;
    float val = S_acc[idx] / fmaxf(cnt[idx >> 7], 1.f);
    if (add) out[idx] += val;
    else     out[idx] = val;
}

// ---------------------------------------------------------------------------
extern "C" void kernel_launch(void* const* d_in, const int* in_sizes, int n_in,
                              void* d_out, int out_size, void* d_ws, size_t ws_size,
                              hipStream_t stream)
{
    const int*   z        = (const int*)d_in[0];
    const float* xyz      = (const float*)d_in[1];
    const float* cg_xyz   = (const float*)d_in[2];
    const int*   mapping  = (const int*)d_in[3];
    const int*   nbr      = (const int*)d_in[4];
    const float* embed    = (const float*)d_in[5];
    const float* msg_W1   = (const float*)d_in[6];
    const float* msg_b1   = (const float*)d_in[7];
    const float* msg_W2   = (const float*)d_in[8];
    const float* msg_b2   = (const float*)d_in[9];
    const float* msg_dW   = (const float*)d_in[10];
    const float* msg_db   = (const float*)d_in[11];
    const float* upd_U    = (const float*)d_in[12];
    const float* upd_V    = (const float*)d_in[13];
    const float* upd_W1   = (const float*)d_in[14];
    const float* upd_b1   = (const float*)d_in[15];
    const float* upd_W2   = (const float*)d_in[16];
    const float* upd_b2   = (const float*)d_in[17];
    const float* cg_W1    = (const float*)d_in[18];
    const float* cg_b1    = (const float*)d_in[19];
    const float* cg_W2    = (const float*)d_in[20];
    const float* cg_b2    = (const float*)d_in[21];
    const float* cg_dW    = (const float*)d_in[22];
    const float* cg_db    = (const float*)d_in[23];
    float* out = (float*)d_out;

    float* ws = (float*)d_ws;
    size_t o = 0;
    float* s      = ws + o; o += PLANE;
    float* vA     = ws + o; o += 3 * PLANE;
    float* vB     = ws + o; o += 3 * PLANE;
    float* uv     = ws + o; o += PLANE;                 // phi_mid scratch
    float* phi    = ws + o; o += (size_t)N_ATOMS * 384; // phi / stack
    float* Cpk    = ws + o; o += (size_t)N_ATOMS * 256; // packed Ccat (hi+lo)
    float* spk    = ws + o; o += PLANE;                 // packed s (hi+lo)
    float* vpk    = ws + o; o += 3 * PLANE;             // packed v (hi+lo)
    float4* rec_u4 = (float4*)(ws + o); o += (size_t)N_EDGES * 4;
    float* rec_rbf = ws + o; o += (size_t)N_EDGES * NRBF;
    int*   rec_dst = (int*)(ws + o); o += N_EDGES;
    float* rbf_a  = ws + o; o += (size_t)N_ATOMS * NRBF;
    float* env_a  = ws + o; o += N_ATOMS;
    float* cnt    = ws + o; o += N_CG;
    float* S_acc  = ws + o; o += N_CG * FEAT;
    int*   deg    = (int*)(ws + o); o += N_ATOMS;
    int*   rowptr = (int*)(ws + o); o += N_ATOMS;
    int*   cursor = (int*)(ws + o); o += N_ATOMS;
    ushort* packH = (ushort*)(ws + o); o += (size_t)NCONV * PACK_PER_CONV / 2;
    ushort* packL = (ushort*)(ws + o); o += (size_t)NCONV * PACK_PER_CONV / 2;

    ushort* CcatH = (ushort*)Cpk; ushort* CcatL = CcatH + (size_t)N_ATOMS * 256;
    ushort* sH = (ushort*)spk;  ushort* sL = sH + PLANE;
    ushort* vH = (ushort*)vpk;  ushort* vL = vH + 3 * PLANE;

    // ---- setup ----
    hipMemsetAsync(vA, 0, sizeof(float) * 3 * PLANE, stream);
    hipMemsetAsync(cnt, 0, sizeof(float) * N_CG, stream);
    hipMemsetAsync(deg, 0, sizeof(int) * N_ATOMS, stream);
    hipMemsetAsync(cursor, 0, sizeof(int) * N_ATOMS, stream);
    k_pack_all<<<dim3(192, 8, 3), 256, 0, stream>>>(msg_W1, msg_W2, upd_V, upd_W1,
                                                    upd_W2, upd_U, cg_W1, cg_W2,
                                                    packH, packL);
    k_s_init<<<(PLANE + 255) / 256, 256, 0, stream>>>(z, embed, s, sH, sL);
    k_atom_geo<<<(N_ATOMS + 255) / 256, 256, 0, stream>>>(mapping, xyz, cg_xyz,
                                                          rbf_a, env_a, cnt);
    k_deg<<<(N_EDGES + 255) / 256, 256, 0, stream>>>(nbr, deg);
    k_scan<<<1, 1024, 0, stream>>>(deg, rowptr);
    k_fill<<<(N_EDGES + 255) / 256, 256, 0, stream>>>(nbr, xyz, rowptr, cursor,
                                                      rec_dst, rec_u4, rec_rbf);

    float* v_cur = vA;
    float* v_nxt = vB;

    for (int i = 0; i < NCONV; ++i) {
        const float* mb1 = msg_b1 + (size_t)i * FEAT;
        const float* mb2 = msg_b2 + (size_t)i * 384;
        const float* mdW = msg_dW + (size_t)i * NRBF * 384;
        const float* mdb = msg_db + (size_t)i * 384;
        const float* ub1 = upd_b1 + (size_t)i * FEAT;
        const float* ub2 = upd_b2 + (size_t)i * 384;
        const float* cb1 = cg_b1  + (size_t)i * FEAT;
        const float* cb2 = cg_b2  + (size_t)i * 384;
        const float* cdW = cg_dW  + (size_t)i * NRBF * 384;
        const float* cdb = cg_db  + (size_t)i * 384;
        const size_t pb  = (size_t)i * PACK_PER_CONV;

        // message block: phi = swish(s@W1+b1)@W2+b2  (one fused kernel)
        mlp_fused<128, 384><<<625, 256, 0, stream>>>(
            sH, sL, packH + pb + 0, packL + pb + 0, mb1,
            packH + pb + 16384, packL + pb + 16384, mb2, 0, phi);
        k_edge_seg<<<EDGE_BLOCKS, 512, 0, stream>>>(rowptr, deg, rec_dst, rec_u4,
                                                    rec_rbf, phi, v_cur, v_nxt, s,
                                                    vH, vL, CcatH, CcatL, mdW, mdb);
        float* vv = v_cur;   // v_cur fp32 dead; reuse as v_v scratch

        // update block
        gemm_vnorm<<<625, 256, 0, stream>>>(vH, vL, packH + pb + 65536,
                                            packL + pb + 65536, vv, CcatH, CcatL);
        mlp_fused<256, 384><<<625, 256, 0, stream>>>(
            CcatH, CcatL, packH + pb + 81920, packL + pb + 81920, ub1,
            packH + pb + 114688, packL + pb + 114688, ub2, 0, phi);   // stack
        gemm_u_update<<<625, 256, 0, stream>>>(vH, vL, packH + pb + 163840,
                                               packL + pb + 163840, vv, phi,
                                               s, v_nxt, sH, sL);

        // CG block (V_I dead; only middle 128 cols of cg_W2)
        mlp_fused<128, 128><<<625, 256, 0, stream>>>(
            sH, sL, packH + pb + 180224, packL + pb + 180224, cb1,
            packH + pb + 196608, packL + pb + 196608, cb2, 128, uv); // phi_mid
        hipMemsetAsync(S_acc, 0, sizeof(float) * N_CG * FEAT, stream);
        k_cg_msg<<<N_ATOMS, 128, 0, stream>>>(mapping, uv, rbf_a, env_a, cdW, cdb,
                                              (i == 0) ? s : nullptr, S_acc);
        k_finalize<<<(N_CG * FEAT + 255) / 256, 256, 0, stream>>>(S_acc, cnt, out,
                                                                  i == 0 ? 0 : 1);

        float* tmp = v_nxt;
        v_nxt = v_cur;
        v_cur = tmp;
    }
}

// Round 2
// 1360.999 us; speedup vs baseline: 1.0744x; 1.0103x over previous
//
#include <hip/hip_runtime.h>
#include <math.h>

#define N_ATOMS 20000
#define N_CG    1000
#define N_EDGES 200000
#define FEAT    128
#define NRBF    20
#define NCONV   3
#define CUTOFF  5.0f
#define PLANE   (N_ATOMS * FEAT)      // 2,560,000
#define PI_F    3.14159265358979323846f
#define LDH     130                   // LDS H stride (f32) — bank-conflict-safe

#define PACK_PER_CONV 212992          // ushorts per conv in each of packH/packL

typedef __attribute__((ext_vector_type(8))) short bf16x8;
typedef __attribute__((ext_vector_type(4))) float f32x4;

__device__ __forceinline__ void split2(float x, ushort& h, ushort& l)
{
    unsigned u  = __float_as_uint(x);
    unsigned hb = (u + 0x7FFFu + ((u >> 16) & 1u)) & 0xFFFF0000u;
    float    hf = __uint_as_float(hb);
    float    lf = x - hf;                       // exact
    unsigned ul = __float_as_uint(lf);
    h = (ushort)(hb >> 16);
    l = (ushort)((ul + 0x7FFFu + ((ul >> 16) & 1u)) >> 16);
}

__device__ __forceinline__ void splitv8(const float* hv, bf16x8& ah, bf16x8& al)
{
#pragma unroll
    for (int j = 0; j < 8; ++j) {
        ushort h, l;
        split2(hv[j], h, l);
        ah[j] = (short)h; al[j] = (short)l;
    }
}

// 3-MFMA split product accumulate
#define MFMA3(ACC, AH_, AL_, BH_, BL_)                                              \
    ACC = __builtin_amdgcn_mfma_f32_16x16x32_bf16(AH_, BH_, ACC, 0, 0, 0);          \
    ACC = __builtin_amdgcn_mfma_f32_16x16x32_bf16(AH_, BL_, ACC, 0, 0, 0);          \
    ACC = __builtin_amdgcn_mfma_f32_16x16x32_bf16(AL_, BH_, ACC, 0, 0, 0);

// ---------------------------------------------------------------------------
// Fused MLP: C = (swish(A @ B1 + b1)) @ B2 + b2[bcol0:].  A packed bf16 hi/lo
// [M][K1]; B1 [128][K1] packed; B2 [N2][128] packed; H held in LDS fp32.
// Block = 32 rows, 256 thr (4 waves 2x2). M must be divisible by 32.
// ---------------------------------------------------------------------------
template<int K1, int N2>
__global__ __launch_bounds__(256)
void mlp_fused(const ushort* __restrict__ AH, const ushort* __restrict__ AL,
               const ushort* __restrict__ B1h, const ushort* __restrict__ B1l,
               const float* __restrict__ b1,
               const ushort* __restrict__ B2h, const ushort* __restrict__ B2l,
               const float* __restrict__ b2, int bcol0,
               float* __restrict__ C)
{
    __shared__ float Hs[32 * LDH];
    const int tid  = threadIdx.x;
    const int lane = tid & 63;
    const int w    = tid >> 6;
    const int wm   = w & 1, wn = w >> 1;
    const int m0   = blockIdx.x * 32;
    const int l15  = lane & 15;
    const int koff = (lane >> 4) * 8;
    const int rowb = wm * 16;                   // local row base
    const int q4   = (lane >> 4) * 4;

    // ---- phase 1: H = swish(A @ B1 + b1) (N1 = 128) ----
    f32x4 acc1[4];
#pragma unroll
    for (int j = 0; j < 4; ++j) acc1[j] = (f32x4){0.f, 0.f, 0.f, 0.f};
    for (int k0 = 0; k0 < K1; k0 += 32) {
        size_t aa = (size_t)(m0 + rowb + l15) * K1 + k0 + koff;
        bf16x8 ah = *reinterpret_cast<const bf16x8*>(AH + aa);
        bf16x8 al = *reinterpret_cast<const bf16x8*>(AL + aa);
#pragma unroll
        for (int nf = 0; nf < 4; ++nf) {
            size_t ba = (size_t)(wn * 64 + nf * 16 + l15) * K1 + k0 + koff;
            bf16x8 bh = *reinterpret_cast<const bf16x8*>(B1h + ba);
            bf16x8 bl = *reinterpret_cast<const bf16x8*>(B1l + ba);
            MFMA3(acc1[nf], ah, al, bh, bl);
        }
    }
#pragma unroll
    for (int nf = 0; nf < 4; ++nf) {
        int col = wn * 64 + nf * 16 + l15;
        float bv = b1[col];
#pragma unroll
        for (int r = 0; r < 4; ++r) {
            float x = acc1[nf][r] + bv;
            x = x / (1.f + __expf(-x));         // swish
            Hs[(rowb + q4 + r) * LDH + col] = x;
        }
    }
    __syncthreads();

    // ---- phase 2: C = H @ B2 + b2 ----
    constexpr int NF2  = N2 / 32;               // frags per wave
    constexpr int WCOL = N2 / 2;
    f32x4 acc2[NF2];
#pragma unroll
    for (int j = 0; j < NF2; ++j) acc2[j] = (f32x4){0.f, 0.f, 0.f, 0.f};
    for (int k0 = 0; k0 < 128; k0 += 32) {
        const float* hp = &Hs[(rowb + l15) * LDH + k0 + koff];
        float hv[8];
#pragma unroll
        for (int j = 0; j < 4; ++j) hv[j] = hp[j];
#pragma unroll
        for (int j = 0; j < 4; ++j) hv[4 + j] = hp[4 + j];
        bf16x8 ah, al;
        splitv8(hv, ah, al);
#pragma unroll
        for (int nf = 0; nf < NF2; ++nf) {
            size_t ba = (size_t)(wn * WCOL + nf * 16 + l15) * 128 + k0 + koff;
            bf16x8 bh = *reinterpret_cast<const bf16x8*>(B2h + ba);
            bf16x8 bl = *reinterpret_cast<const bf16x8*>(B2l + ba);
            MFMA3(acc2[nf], ah, al, bh, bl);
        }
    }
#pragma unroll
    for (int nf = 0; nf < NF2; ++nf) {
        int col = wn * WCOL + nf * 16 + l15;
        float bv = b2 ? b2[bcol0 + col] : 0.f;
#pragma unroll
        for (int r = 0; r < 4; ++r) {
            int row = m0 + rowb + q4 + r;
            C[(size_t)row * N2 + col] = acc2[nf][r] + bv;
        }
    }
}

// ---------------------------------------------------------------------------
// upd_V over 3 planes + fused norm + Ccat norm-half pack.
// A = packed v (3 planes), B = upd_V. Writes vv fp32 (3 planes) + Ccat[,128:].
// ---------------------------------------------------------------------------
__global__ __launch_bounds__(256)
void gemm_vnorm(const ushort* __restrict__ vHp, const ushort* __restrict__ vLp,
                const ushort* __restrict__ Bh, const ushort* __restrict__ Bl,
                float* __restrict__ vv,
                ushort* __restrict__ CcatH, ushort* __restrict__ CcatL)
{
    const int tid  = threadIdx.x;
    const int lane = tid & 63;
    const int w    = tid >> 6;
    const int wm   = w & 1, wn = w >> 1;
    const int m0   = blockIdx.x * 32;
    const int l15  = lane & 15;
    const int koff = (lane >> 4) * 8;
    const int rowb = wm * 16;
    const int q4   = (lane >> 4) * 4;

    f32x4 acc[3][4];
#pragma unroll
    for (int d = 0; d < 3; ++d)
#pragma unroll
        for (int j = 0; j < 4; ++j) acc[d][j] = (f32x4){0.f, 0.f, 0.f, 0.f};

    for (int k0 = 0; k0 < 128; k0 += 32) {
        bf16x8 ah[3], al[3];
#pragma unroll
        for (int d = 0; d < 3; ++d) {
            size_t aa = (size_t)d * PLANE + (size_t)(m0 + rowb + l15) * 128 + k0 + koff;
            ah[d] = *reinterpret_cast<const bf16x8*>(vHp + aa);
            al[d] = *reinterpret_cast<const bf16x8*>(vLp + aa);
        }
#pragma unroll
        for (int nf = 0; nf < 4; ++nf) {
            size_t ba = (size_t)(wn * 64 + nf * 16 + l15) * 128 + k0 + koff;
            bf16x8 bh = *reinterpret_cast<const bf16x8*>(Bh + ba);
            bf16x8 bl = *reinterpret_cast<const bf16x8*>(Bl + ba);
#pragma unroll
            for (int d = 0; d < 3; ++d) {
                MFMA3(acc[d][nf], ah[d], al[d], bh, bl);
            }
        }
    }
#pragma unroll
    for (int nf = 0; nf < 4; ++nf) {
        int col = wn * 64 + nf * 16 + l15;
#pragma unroll
        for (int r = 0; r < 4; ++r) {
            int row = m0 + rowb + q4 + r;
            int idx = row * FEAT + col;
            float x = acc[0][nf][r], y = acc[1][nf][r], z = acc[2][nf][r];
            vv[idx] = x; vv[PLANE + idx] = y; vv[2 * PLANE + idx] = z;
            float nrm = sqrtf(x * x + y * y + z * z + 3e-15f);
            ushort h, l;
            split2(nrm, h, l);
            CcatH[(size_t)row * 256 + 128 + col] = h;
            CcatL[(size_t)row * 256 + 128 + col] = l;
        }
    }
}

// ---------------------------------------------------------------------------
// upd_U over 3 planes + fused update rule.
// u_v in-register; reads vv/stack/v/s; writes s, v (fp32 + packed).
// Blocks own disjoint rows -> in-place overwrite of packed v is race-free.
// ---------------------------------------------------------------------------
__global__ __launch_bounds__(256)
void gemm_u_update(const ushort* __restrict__ vHp, const ushort* __restrict__ vLp,
                   const ushort* __restrict__ Bh, const ushort* __restrict__ Bl,
                   const float* __restrict__ vv, const float* __restrict__ stack,
                   float* __restrict__ s, float* __restrict__ v,
                   ushort* __restrict__ sH, ushort* __restrict__ sL)
{
    const int tid  = threadIdx.x;
    const int lane = tid & 63;
    const int w    = tid >> 6;
    const int wm   = w & 1, wn = w >> 1;
    const int m0   = blockIdx.x * 32;
    const int l15  = lane & 15;
    const int koff = (lane >> 4) * 8;
    const int rowb = wm * 16;
    const int q4   = (lane >> 4) * 4;

    f32x4 acc[3][4];
#pragma unroll
    for (int d = 0; d < 3; ++d)
#pragma unroll
        for (int j = 0; j < 4; ++j) acc[d][j] = (f32x4){0.f, 0.f, 0.f, 0.f};

    for (int k0 = 0; k0 < 128; k0 += 32) {
        bf16x8 ah[3], al[3];
#pragma unroll
        for (int d = 0; d < 3; ++d) {
            size_t aa = (size_t)d * PLANE + (size_t)(m0 + rowb + l15) * 128 + k0 + koff;
            ah[d] = *reinterpret_cast<const bf16x8*>(vHp + aa);
            al[d] = *reinterpret_cast<const bf16x8*>(vLp + aa);
        }
#pragma unroll
        for (int nf = 0; nf < 4; ++nf) {
            size_t ba = (size_t)(wn * 64 + nf * 16 + l15) * 128 + k0 + koff;
            bf16x8 bh = *reinterpret_cast<const bf16x8*>(Bh + ba);
            bf16x8 bl = *reinterpret_cast<const bf16x8*>(Bl + ba);
#pragma unroll
            for (int d = 0; d < 3; ++d) {
                MFMA3(acc[d][nf], ah[d], al[d], bh, bl);
            }
        }
    }
    // packed v overwrite below is safe: this block's A reads (own rows) are done
    ushort* vHo = const_cast<ushort*>(vHp);
    ushort* vLo = const_cast<ushort*>(vLp);
#pragma unroll
    for (int nf = 0; nf < 4; ++nf) {
        int col = wn * 64 + nf * 16 + l15;
#pragma unroll
        for (int r = 0; r < 4; ++r) {
            int row = m0 + rowb + q4 + r;
            int idx = row * FEAT + col;
            const float* st = stack + (size_t)row * 384 + col;
            float avv = st[0], asv = st[128], ass = st[256];
            float u0 = acc[0][nf][r], u1 = acc[1][nf][r], u2 = acc[2][nf][r];
            float w0 = vv[idx], w1 = vv[PLANE + idx], w2 = vv[2 * PLANE + idx];
            float dot = u0 * w0 + u1 * w1 + u2 * w2;
            float n0 = v[idx]             + u0 * avv;
            float n1 = v[PLANE + idx]     + u1 * avv;
            float n2 = v[2 * PLANE + idx] + u2 * avv;
            v[idx] = n0; v[PLANE + idx] = n1; v[2 * PLANE + idx] = n2;
            ushort h, l;
            split2(n0, h, l); vHo[idx] = h;             vLo[idx] = l;
            split2(n1, h, l); vHo[PLANE + idx] = h;     vLo[PLANE + idx] = l;
            split2(n2, h, l); vHo[2 * PLANE + idx] = h; vLo[2 * PLANE + idx] = l;
            float ns = s[idx] + dot * asv + ass;
            s[idx] = ns;
            split2(ns, h, l); sH[idx] = h; sL[idx] = l;
        }
    }
}

// ---------------------------------------------------------------------------
// Weight pre-pack: fp32 W[k][col0+n] -> bf16 hi/lo at [n][k] (k-contiguous).
// ---------------------------------------------------------------------------
__global__ void k_pack_all(const float* __restrict__ msg_W1, const float* __restrict__ msg_W2,
                           const float* __restrict__ upd_V,  const float* __restrict__ upd_W1,
                           const float* __restrict__ upd_W2, const float* __restrict__ upd_U,
                           const float* __restrict__ cg_W1,  const float* __restrict__ cg_W2,
                           ushort* __restrict__ Bh, ushort* __restrict__ Bl)
{
    const int wid = blockIdx.y, conv = blockIdx.z;
    const float* W; int K, N, ldw, col0; size_t off;
    switch (wid) {
        case 0: W = msg_W1 + (size_t)conv * 16384; K = 128; N = 128; ldw = 128; col0 = 0;   off = 0;      break;
        case 1: W = msg_W2 + (size_t)conv * 49152; K = 128; N = 384; ldw = 384; col0 = 0;   off = 16384;  break;
        case 2: W = upd_V  + (size_t)conv * 16384; K = 128; N = 128; ldw = 128; col0 = 0;   off = 65536;  break;
        case 3: W = upd_W1 + (size_t)conv * 32768; K = 256; N = 128; ldw = 128; col0 = 0;   off = 81920;  break;
        case 4: W = upd_W2 + (size_t)conv * 49152; K = 128; N = 384; ldw = 384; col0 = 0;   off = 114688; break;
        case 5: W = upd_U  + (size_t)conv * 16384; K = 128; N = 128; ldw = 128; col0 = 0;   off = 163840; break;
        case 6: W = cg_W1  + (size_t)conv * 16384; K = 128; N = 128; ldw = 128; col0 = 0;   off = 180224; break;
        default:W = cg_W2  + (size_t)conv * 49152; K = 128; N = 128; ldw = 384; col0 = 128; off = 196608; break;
    }
    off += (size_t)conv * PACK_PER_CONV;
    int idx = blockIdx.x * 256 + threadIdx.x;
    if (idx >= K * N) return;
    int k = idx & (K - 1);
    int n = idx >> ((K == 256) ? 8 : 7);
    ushort h, l;
    split2(W[(size_t)k * ldw + col0 + n], h, l);
    Bh[off + (size_t)n * K + k] = h;
    Bl[off + (size_t)n * K + k] = l;
}

// ---------------------------------------------------------------------------
// Setup kernels
// ---------------------------------------------------------------------------
__global__ void k_s_init(const int* __restrict__ z, const float* __restrict__ embed,
                         float* __restrict__ s, ushort* __restrict__ sH, ushort* __restrict__ sL)
{
    int idx = blockIdx.x * blockDim.x + threadIdx.x;
    if (idx >= PLANE) return;
    int n = idx >> 7, g = idx & 127;
    float e = embed[z[n] * FEAT + g];
    s[idx] = e;
    ushort h, l;
    split2(e, h, l);
    sH[idx] = h; sL[idx] = l;
}

__global__ void k_atom_geo(const int* __restrict__ mapping,
                           const float* __restrict__ xyz, const float* __restrict__ cg_xyz,
                           float* __restrict__ rbf_a, float* __restrict__ env_a,
                           float* __restrict__ cnt)
{
    int n = blockIdx.x * blockDim.x + threadIdx.x;
    if (n >= N_ATOMS) return;
    int m = mapping[n];
    float dx = xyz[n * 3 + 0] - cg_xyz[m * 3 + 0];
    float dy = xyz[n * 3 + 1] - cg_xyz[m * 3 + 1];
    float dz = xyz[n * 3 + 2] - cg_xyz[m * 3 + 2];
    float d = sqrtf(dx * dx + dy * dy + dz * dz + 3e-15f);
    float env = (d < CUTOFF) ? 0.5f * (cosf(PI_F * d / CUTOFF) + 1.f) : 0.f;
    env_a[n] = env;
    float s = env / d;
#pragma unroll
    for (int k = 0; k < NRBF; ++k)
        rbf_a[n * NRBF + k] = sinf((k + 1) * PI_F * d / CUTOFF) * s;
    atomicAdd(&cnt[m], 1.f);
}

// ---------------------------------------------------------------------------
// CSR build
// ---------------------------------------------------------------------------
__global__ void k_deg(const int* __restrict__ nbr, int* __restrict__ deg)
{
    int e = blockIdx.x * blockDim.x + threadIdx.x;
    if (e < N_EDGES) atomicAdd(&deg[nbr[2 * e]], 1);
}

__global__ __launch_bounds__(1024)
void k_scan(const int* __restrict__ deg, int* __restrict__ rowptr)
{
    __shared__ int sh[1024];
    const int chunk = (N_ATOMS + 1023) / 1024;
    int t = threadIdx.x;
    int base = t * chunk;
    int sum = 0;
    for (int i = 0; i < chunk; ++i) {
        int idx = base + i;
        if (idx < N_ATOMS) sum += deg[idx];
    }
    sh[t] = sum;
    __syncthreads();
    for (int off = 1; off < 1024; off <<= 1) {
        int val = (t >= off) ? sh[t - off] : 0;
        __syncthreads();
        sh[t] += val;
        __syncthreads();
    }
    int run = (t == 0) ? 0 : sh[t - 1];
    for (int i = 0; i < chunk; ++i) {
        int idx = base + i;
        if (idx < N_ATOMS) { rowptr[idx] = run; run += deg[idx]; }
    }
}

__global__ void k_fill(const int* __restrict__ nbr, const float* __restrict__ xyz,
                       const int* __restrict__ rowptr, int* __restrict__ cursor,
                       int* __restrict__ rec_dst, float4* __restrict__ rec_u4,
                       float* __restrict__ rec_rbf)
{
    int e = blockIdx.x * blockDim.x + threadIdx.x;
    if (e >= N_EDGES) return;
    int src = nbr[2 * e], dst = nbr[2 * e + 1];
    int pos = atomicAdd(&cursor[src], 1);
    int q = rowptr[src] + pos;
    float dx = xyz[dst * 3 + 0] - xyz[src * 3 + 0];
    float dy = xyz[dst * 3 + 1] - xyz[src * 3 + 1];
    float dz = xyz[dst * 3 + 2] - xyz[src * 3 + 2];
    float d = sqrtf(dx * dx + dy * dy + dz * dz + 3e-15f);
    float env = (d < CUTOFF) ? 0.5f * (cosf(PI_F * d / CUTOFF) + 1.f) : 0.f;
    rec_dst[q] = dst;
    rec_u4[q] = make_float4(dx / d, dy / d, dz / d, env);
    float sc = env / d;
#pragma unroll
    for (int k = 0; k < NRBF; ++k)
        rec_rbf[(size_t)q * NRBF + k] = sinf((k + 1) * PI_F * d / CUTOFF) * sc;
}

// ---------------------------------------------------------------------------
// Edge segment-sum.  r1 change: one 128-thread slot (2 waves) OWNS one atom —
// no cross-slot reduction, no LDS, no __syncthreads.  Each slot streams its
// atom's edge list serially; wave-pairs are fully independent so gather
// latency (rec_dst -> phi/v_in chain, ~200-900 cyc) hides via TLP.  Weight
// table stays in VGPRs (63 regs/lane); launch_bounds(512,4) caps VGPR at 128
// so they genuinely fit without re-loads.  Epilogue runs on all 128 lanes.
// ---------------------------------------------------------------------------
#define EDGE_BLOCKS 2500
__global__ __launch_bounds__(512, 4)
void k_edge_seg(const int* __restrict__ rowptr, const int* __restrict__ deg,
                const int* __restrict__ rec_dst, const float4* __restrict__ rec_u4,
                const float* __restrict__ rec_rbf,
                const float* __restrict__ phi,
                const float* __restrict__ v_in, float* __restrict__ v_out,
                float* __restrict__ s,
                ushort* __restrict__ vH, ushort* __restrict__ vL,
                ushort* __restrict__ CcatH, ushort* __restrict__ CcatL,
                const float* __restrict__ distW, const float* __restrict__ distb)
{
    const int tid    = threadIdx.x;
    const int slot   = tid >> 7;                // 0..3 within block
    const int f      = tid & 127;
    const int slot_g = blockIdx.x * 4 + slot;   // global slot id
    const int nslots = EDGE_BLOCKS * 4;         // 10000 slots, 2 atoms each

    // per-lane weight registers: k=20 is the bias row
    float wx[21], wy[21], wz[21];
#pragma unroll
    for (int k = 0; k < NRBF; ++k) {
        wx[k] = distW[k * 384 + f];
        wy[k] = distW[k * 384 + 128 + f];
        wz[k] = distW[k * 384 + 256 + f];
    }
    wx[20] = distb[f];
    wy[20] = distb[128 + f];
    wz[20] = distb[256 + f];

    for (int a = slot_g; a < N_ATOMS; a += nslots) {
        const int beg = rowptr[a];
        const int end = beg + deg[a];
        float s_acc = 0.f, vx = 0.f, vy = 0.f, vz = 0.f;

        for (int p = beg; p < end; ++p) {
            float4 u4 = rec_u4[p];
            int dst = rec_dst[p];
            if (u4.w == 0.f) continue;          // fully-dead edge (slot-uniform)
            const float* ph = phi + (size_t)dst * 384 + f;
            float p0 = ph[0], p1 = ph[128], p2 = ph[256];
            int di = dst * FEAT + f;
            float vdx = v_in[di], vdy = v_in[PLANE + di], vdz = v_in[2 * PLANE + di];
            const float4* rbp = reinterpret_cast<const float4*>(rec_rbf + (size_t)p * NRBF);
            float4 r0 = rbp[0], r1 = rbp[1], r2 = rbp[2], r3 = rbp[3], r4 = rbp[4];
            const float rr[21] = {r0.x, r0.y, r0.z, r0.w, r1.x, r1.y, r1.z, r1.w,
                                  r2.x, r2.y, r2.z, r2.w, r3.x, r3.y, r3.z, r3.w,
                                  r4.x, r4.y, r4.z, r4.w, u4.w};
            float w0 = 0.f, w1 = 0.f, w2 = 0.f;
#pragma unroll
            for (int k = 0; k < 21; ++k) {
                w0 += rr[k] * wx[k];
                w1 += rr[k] * wy[k];
                w2 += rr[k] * wz[k];
            }
            float i0 = p0 * w0, i1 = p1 * w1, i2 = p2 * w2;
            vx += i2 * u4.x + i0 * vdx;
            vy += i2 * u4.y + i0 * vdy;
            vz += i2 * u4.z + i0 * vdz;
            s_acc += i1;
        }

        // epilogue: this slot's 128 lanes write atom a's outputs
        int si = a * FEAT + f;
        float ns = s[si] + s_acc;
        s[si] = ns;
        float nx = v_in[si]             + vx;
        float ny = v_in[PLANE + si]     + vy;
        float nz = v_in[2 * PLANE + si] + vz;
        v_out[si] = nx; v_out[PLANE + si] = ny; v_out[2 * PLANE + si] = nz;
        ushort h, l;
        split2(nx, h, l); vH[si] = h;             vL[si] = l;
        split2(ny, h, l); vH[PLANE + si] = h;     vL[PLANE + si] = l;
        split2(nz, h, l); vH[2 * PLANE + si] = h; vL[2 * PLANE + si] = l;
        split2(ns, h, l);
        CcatH[(size_t)a * 256 + f] = h;
        CcatL[(size_t)a * 256 + f] = l;
    }
}

// CG message; conv0 also scatters s (s_add path)
__global__ __launch_bounds__(128)
void k_cg_msg(const int* __restrict__ mapping, const float* __restrict__ phi_mid,
              const float* __restrict__ rbf_a, const float* __restrict__ env_a,
              const float* __restrict__ distW, const float* __restrict__ distb,
              const float* __restrict__ s_add, float* __restrict__ S_acc)
{
    int n = blockIdx.x;
    float env = env_a[n];
    int f = threadIdx.x;
    if (env == 0.f && s_add == nullptr) return;
    float val = s_add ? s_add[n * FEAT + f] : 0.f;
    if (env != 0.f) {
        __shared__ float sh_rbf[NRBF];
        if (f < NRBF) sh_rbf[f] = rbf_a[n * NRBF + f];
        __syncthreads();
        float w1 = 0.f;
#pragma unroll
        for (int k = 0; k < NRBF; ++k)
            w1 += sh_rbf[k] * distW[k * 384 + 128 + f];
        w1 += distb[128 + f] * env;
        val += phi_mid[n * FEAT + f] * w1;
    }
    atomicAdd(&S_acc[mapping[n] * FEAT + f], val);
}

__global__ void k_finalize(const float* __restrict__ S_acc, const float* __restrict__ cnt,
                           float* __restrict__ out, int add)
{
    int idx = blockIdx.x * blockDim.x + threadIdx.x;
    if (idx >= N_CG * FEAT) return;
    float val = S_acc[idx] / fmaxf(cnt[idx >> 7], 1.f);
    if (add) out[idx] += val;
    else     out[idx] = val;
}

// ---------------------------------------------------------------------------
extern "C" void kernel_launch(void* const* d_in, const int* in_sizes, int n_in,
                              void* d_out, int out_size, void* d_ws, size_t ws_size,
                              hipStream_t stream)
{
    const int*   z        = (const int*)d_in[0];
    const float* xyz      = (const float*)d_in[1];
    const float* cg_xyz   = (const float*)d_in[2];
    const int*   mapping  = (const int*)d_in[3];
    const int*   nbr      = (const int*)d_in[4];
    const float* embed    = (const float*)d_in[5];
    const float* msg_W1   = (const float*)d_in[6];
    const float* msg_b1   = (const float*)d_in[7];
    const float* msg_W2   = (const float*)d_in[8];
    const float* msg_b2   = (const float*)d_in[9];
    const float* msg_dW   = (const float*)d_in[10];
    const float* msg_db   = (const float*)d_in[11];
    const float* upd_U    = (const float*)d_in[12];
    const float* upd_V    = (const float*)d_in[13];
    const float* upd_W1   = (const float*)d_in[14];
    const float* upd_b1   = (const float*)d_in[15];
    const float* upd_W2   = (const float*)d_in[16];
    const float* upd_b2   = (const float*)d_in[17];
    const float* cg_W1    = (const float*)d_in[18];
    const float* cg_b1    = (const float*)d_in[19];
    const float* cg_W2    = (const float*)d_in[20];
    const float* cg_b2    = (const float*)d_in[21];
    const float* cg_dW    = (const float*)d_in[22];
    const float* cg_db    = (const float*)d_in[23];
    float* out = (float*)d_out;

    float* ws = (float*)d_ws;
    size_t o = 0;
    float* s      = ws + o; o += PLANE;
    float* vA     = ws + o; o += 3 * PLANE;
    float* vB     = ws + o; o += 3 * PLANE;
    float* uv     = ws + o; o += PLANE;                 // phi_mid scratch
    float* phi    = ws + o; o += (size_t)N_ATOMS * 384; // phi / stack
    float* Cpk    = ws + o; o += (size_t)N_ATOMS * 256; // packed Ccat (hi+lo)
    float* spk    = ws + o; o += PLANE;                 // packed s (hi+lo)
    float* vpk    = ws + o; o += 3 * PLANE;             // packed v (hi+lo)
    float4* rec_u4 = (float4*)(ws + o); o += (size_t)N_EDGES * 4;
    float* rec_rbf = ws + o; o += (size_t)N_EDGES * NRBF;
    int*   rec_dst = (int*)(ws + o); o += N_EDGES;
    float* rbf_a  = ws + o; o += (size_t)N_ATOMS * NRBF;
    float* env_a  = ws + o; o += N_ATOMS;
    float* cnt    = ws + o; o += N_CG;
    float* S_acc  = ws + o; o += N_CG * FEAT;
    int*   deg    = (int*)(ws + o); o += N_ATOMS;
    int*   rowptr = (int*)(ws + o); o += N_ATOMS;
    int*   cursor = (int*)(ws + o); o += N_ATOMS;
    ushort* packH = (ushort*)(ws + o); o += (size_t)NCONV * PACK_PER_CONV / 2;
    ushort* packL = (ushort*)(ws + o); o += (size_t)NCONV * PACK_PER_CONV / 2;

    ushort* CcatH = (ushort*)Cpk; ushort* CcatL = CcatH + (size_t)N_ATOMS * 256;
    ushort* sH = (ushort*)spk;  ushort* sL = sH + PLANE;
    ushort* vH = (ushort*)vpk;  ushort* vL = vH + 3 * PLANE;

    // ---- setup ----
    hipMemsetAsync(vA, 0, sizeof(float) * 3 * PLANE, stream);
    hipMemsetAsync(cnt, 0, sizeof(float) * N_CG, stream);
    hipMemsetAsync(deg, 0, sizeof(int) * N_ATOMS, stream);
    hipMemsetAsync(cursor, 0, sizeof(int) * N_ATOMS, stream);
    k_pack_all<<<dim3(192, 8, 3), 256, 0, stream>>>(msg_W1, msg_W2, upd_V, upd_W1,
                                                    upd_W2, upd_U, cg_W1, cg_W2,
                                                    packH, packL);
    k_s_init<<<(PLANE + 255) / 256, 256, 0, stream>>>(z, embed, s, sH, sL);
    k_atom_geo<<<(N_ATOMS + 255) / 256, 256, 0, stream>>>(mapping, xyz, cg_xyz,
                                                          rbf_a, env_a, cnt);
    k_deg<<<(N_EDGES + 255) / 256, 256, 0, stream>>>(nbr, deg);
    k_scan<<<1, 1024, 0, stream>>>(deg, rowptr);
    k_fill<<<(N_EDGES + 255) / 256, 256, 0, stream>>>(nbr, xyz, rowptr, cursor,
                                                      rec_dst, rec_u4, rec_rbf);

    float* v_cur = vA;
    float* v_nxt = vB;

    for (int i = 0; i < NCONV; ++i) {
        const float* mb1 = msg_b1 + (size_t)i * FEAT;
        const float* mb2 = msg_b2 + (size_t)i * 384;
        const float* mdW = msg_dW + (size_t)i * NRBF * 384;
        const float* mdb = msg_db + (size_t)i * 384;
        const float* ub1 = upd_b1 + (size_t)i * FEAT;
        const float* ub2 = upd_b2 + (size_t)i * 384;
        const float* cb1 = cg_b1  + (size_t)i * FEAT;
        const float* cb2 = cg_b2  + (size_t)i * 384;
        const float* cdW = cg_dW  + (size_t)i * NRBF * 384;
        const float* cdb = cg_db  + (size_t)i * 384;
        const size_t pb  = (size_t)i * PACK_PER_CONV;

        // message block: phi = swish(s@W1+b1)@W2+b2  (one fused kernel)
        mlp_fused<128, 384><<<625, 256, 0, stream>>>(
            sH, sL, packH + pb + 0, packL + pb + 0, mb1,
            packH + pb + 16384, packL + pb + 16384, mb2, 0, phi);
        k_edge_seg<<<EDGE_BLOCKS, 512, 0, stream>>>(rowptr, deg, rec_dst, rec_u4,
                                                    rec_rbf, phi, v_cur, v_nxt, s,
                                                    vH, vL, CcatH, CcatL, mdW, mdb);
        float* vv = v_cur;   // v_cur fp32 dead; reuse as v_v scratch

        // update block
        gemm_vnorm<<<625, 256, 0, stream>>>(vH, vL, packH + pb + 65536,
                                            packL + pb + 65536, vv, CcatH, CcatL);
        mlp_fused<256, 384><<<625, 256, 0, stream>>>(
            CcatH, CcatL, packH + pb + 81920, packL + pb + 81920, ub1,
            packH + pb + 114688, packL + pb + 114688, ub2, 0, phi);   // stack
        gemm_u_update<<<625, 256, 0, stream>>>(vH, vL, packH + pb + 163840,
                                               packL + pb + 163840, vv, phi,
                                               s, v_nxt, sH, sL);

        // CG block (V_I dead; only middle 128 cols of cg_W2)
        mlp_fused<128, 128><<<625, 256, 0, stream>>>(
            sH, sL, packH + pb + 180224, packL + pb + 180224, cb1,
            packH + pb + 196608, packL + pb + 196608, cb2, 128, uv); // phi_mid
        hipMemsetAsync(S_acc, 0, sizeof(float) * N_CG * FEAT, stream);
        k_cg_msg<<<N_ATOMS, 128, 0, stream>>>(mapping, uv, rbf_a, env_a, cdW, cdb,
                                              (i == 0) ? s : nullptr, S_acc);
        k_finalize<<<(N_CG * FEAT + 255) / 256, 256, 0, stream>>>(S_acc, cnt, out,
                                                                  i == 0 ? 0 : 1);

        float* tmp = v_nxt;
        v_nxt = v_cur;
        v_cur = tmp;
    }
}